// Round 7
// baseline (1313.213 us; speedup 1.0000x reference)
//
#include <hip/hip_runtime.h>
#include <stdint.h>

// CA model constants (match reference)
#define BB 8
#define CC 16
#define HH_ 128
#define WW 128
#define HIDN 128
#define HWSZ (HH_ * WW)          // 16384
#define NPIX (BB * HWSZ)         // 131072
#define NSTEPS 16

// ---------------------------------------------------------------------------
// Threefry-2x32, 20 rounds — exact JAX implementation (partitionable mode).
// ---------------------------------------------------------------------------
__host__ __device__ inline void threefry2x32(uint32_t k0, uint32_t k1,
                                             uint32_t x0, uint32_t x1,
                                             uint32_t* o0, uint32_t* o1) {
  uint32_t ks[3] = {k0, k1, k0 ^ k1 ^ 0x1BD11BDAu};
  const uint32_t rots[2][4] = {{13u, 15u, 26u, 6u}, {17u, 29u, 16u, 24u}};
  x0 += ks[0];
  x1 += ks[1];
#pragma unroll
  for (int g = 0; g < 5; ++g) {
    const uint32_t* r = rots[g & 1];
#pragma unroll
    for (int i = 0; i < 4; ++i) {
      x0 += x1;
      x1 = (x1 << r[i]) | (x1 >> (32u - r[i]));
      x1 ^= x0;
    }
    x0 += ks[(g + 1) % 3];
    x1 += ks[(g + 2) % 3] + (uint32_t)(g + 1);
  }
  *o0 = x0;
  *o1 = x1;
}

__device__ __forceinline__ float jax_mask_bit(uint32_t key0, uint32_t key1, int g) {
  uint32_t t0, t1;
  threefry2x32(key0, key1, 0u, (uint32_t)g, &t0, &t1);
  uint32_t bits = t0 ^ t1;
  float u = __uint_as_float((bits >> 9) | 0x3f800000u) - 1.0f;
  return (u < 0.5f) ? 1.0f : 0.0f;
}

#define FMA4(acc, wv, pp, k)          \
  acc = fmaf(wv.x, pp[(k) + 0], acc); \
  acc = fmaf(wv.y, pp[(k) + 1], acc); \
  acc = fmaf(wv.z, pp[(k) + 2], acc); \
  acc = fmaf(wv.w, pp[(k) + 3], acc);

// ---------------------------------------------------------------------------
// Kernel A: sobel perception + MLP + mask -> writes "new" state to nxt.
// 256 thr/block, 2 px/thread (vertical pair), grid=256 -> 1 block/CU,
// 4 waves/CU (1/SIMD), launch_bounds(256,1) for a 512-VGPR budget.
// ALL weights from LDS (no SMEM in hot loop -> no lgkmcnt conflation);
// w1 row ping-pong double-buffered in registers one hh ahead.
// Per hh: 17 broadcast LDS instrs vs 128 FMAs/lane.
// ---------------------------------------------------------------------------
__global__ __launch_bounds__(256, 1) void ca_step_mlp(
    const float* __restrict__ cur, const float* __restrict__ w1,
    const float* __restrict__ b1, const float* __restrict__ w2,
    const float* __restrict__ b2, float* __restrict__ nxt,
    uint32_t key0, uint32_t key1) {
  __shared__ float lw1[HIDN * 48];   // 24576 B, [hh][48]
  __shared__ float lw2t[HIDN * CC];  // 8192 B, [hh][o]
  __shared__ float lb1[HIDN];        // 512 B

  // --- staging (one-time; weights are L2-hot after step 0) ---
  {
    const float4* gw1 = (const float4*)w1;
    float4* s1 = (float4*)lw1;
    for (int i = threadIdx.x; i < HIDN * 12; i += 256) s1[i] = gw1[i];
    for (int i = threadIdx.x; i < HIDN * CC; i += 256) {
      int hh = i >> 4, o = i & 15;
      lw2t[i] = w2[o * HIDN + hh];
    }
    if (threadIdx.x < HIDN) lb1[threadIdx.x] = b1[threadIdx.x];
  }
  __syncthreads();

  // --- pixel mapping: block covers 4 rows of one image; thread = (rpair,col)
  const int blk = blockIdx.x;        // 0..255
  const int b = blk >> 5;            // image 0..7
  const int R = (blk & 31) * 4;      // base row 0,4,...,124
  const int col = threadIdx.x & 127;
  const int rp = threadIdx.x >> 7;   // 0 or 1
  const int r = R + 2 * rp;          // even row of this thread's pair
  const int hw0 = r * WW + col;
  const int g0 = b * HWSZ + hw0;     // px0 flat; px1 = g0 + WW

  const bool hu = r > 0, hd = r < HH_ - 2, wl = col > 0, wr = col < WW - 1;
  const int du = hu ? -WW : 0;       // row r-1
  const int dd = hd ? 2 * WW : 0;    // row r+2
  const int dl = wl ? -1 : 0;
  const int dr = wr ? 1 : 0;

  const float* xb = cur + (size_t)b * CC * HWSZ + hw0;

  // perception for both pixels: [ident(16) | sx(16) | sy(16)]
  float p0[48], p1[48];
#pragma unroll
  for (int c = 0; c < CC; ++c) {
    const float* xc = xb + c * HWSZ;
    // 4 stencil rows (r-1, r, r+1, r+2) x 3 cols = 12 loads for 2 pixels
    float A0l = xc[du + dl], A0m = xc[du], A0r = xc[du + dr];
    if (!hu) { A0l = 0.f; A0m = 0.f; A0r = 0.f; }
    else { if (!wl) A0l = 0.f; if (!wr) A0r = 0.f; }
    float A1l = xc[dl], A1m = xc[0], A1r = xc[dr];
    if (!wl) A1l = 0.f;
    if (!wr) A1r = 0.f;
    float A2l = xc[WW + dl], A2m = xc[WW], A2r = xc[WW + dr];  // row r+1 valid
    if (!wl) A2l = 0.f;
    if (!wr) A2r = 0.f;
    float A3l = xc[dd + dl], A3m = xc[dd], A3r = xc[dd + dr];
    if (!hd) { A3l = 0.f; A3m = 0.f; A3r = 0.f; }
    else { if (!wl) A3l = 0.f; if (!wr) A3r = 0.f; }

    p0[c] = A1m;
    p0[16 + c] = (A0l - A0r + 2.f * (A1l - A1r) + A2l - A2r) * 0.125f;
    p0[32 + c] = (A0l + 2.f * A0m + A0r - A2l - 2.f * A2m - A2r) * 0.125f;
    p1[c] = A2m;
    p1[16 + c] = (A1l - A1r + 2.f * (A2l - A2r) + A3l - A3r) * 0.125f;
    p1[32 + c] = (A1l + 2.f * A1m + A1r - A3l - 2.f * A3m - A3r) * 0.125f;
  }

  float diff0[CC], diff1[CC];
#pragma unroll
  for (int o = 0; o < CC; ++o) {
    float bo = b2[o];  // uniform -> s_load, before the loop
    diff0[o] = bo;
    diff1[o] = bo;
  }

  const float4* lw = (const float4*)lw1;  // [hh*12 + q]
  float4 wA[12], wB[12];
#pragma unroll
  for (int q = 0; q < 12; ++q) wA[q] = lw[q];  // preload row 0

  for (int chunk = 0; chunk < 8; ++chunk) {
#pragma unroll
    for (int j = 0; j < 16; ++j) {
      const int hh = chunk * 16 + j;
      const int hnx = (hh + 1) & 127;
      float4* pb = (j & 1) ? wA : wB;        // static under full unroll
      const float4* cb = (j & 1) ? wB : wA;
#pragma unroll
      for (int q = 0; q < 12; ++q) pb[q] = lw[hnx * 12 + q];  // prefetch hh+1

      const float4* w2r = (const float4*)(lw2t + hh * CC);
      float4 u0 = w2r[0], u1 = w2r[1], u2 = w2r[2], u3 = w2r[3];
      const float bb = lb1[hh];

      float a0 = bb, a1 = 0.f, a2 = 0.f, a3 = 0.f;  // px0
      float c0 = bb, c1 = 0.f, c2 = 0.f, c3 = 0.f;  // px1
      FMA4(a0, cb[0], p0, 0)
      FMA4(a1, cb[1], p0, 4)
      FMA4(a2, cb[2], p0, 8)
      FMA4(a3, cb[3], p0, 12)
      FMA4(a0, cb[4], p0, 16)
      FMA4(a1, cb[5], p0, 20)
      FMA4(a2, cb[6], p0, 24)
      FMA4(a3, cb[7], p0, 28)
      FMA4(a0, cb[8], p0, 32)
      FMA4(a1, cb[9], p0, 36)
      FMA4(a2, cb[10], p0, 40)
      FMA4(a3, cb[11], p0, 44)
      FMA4(c0, cb[0], p1, 0)
      FMA4(c1, cb[1], p1, 4)
      FMA4(c2, cb[2], p1, 8)
      FMA4(c3, cb[3], p1, 12)
      FMA4(c0, cb[4], p1, 16)
      FMA4(c1, cb[5], p1, 20)
      FMA4(c2, cb[6], p1, 24)
      FMA4(c3, cb[7], p1, 28)
      FMA4(c0, cb[8], p1, 32)
      FMA4(c1, cb[9], p1, 36)
      FMA4(c2, cb[10], p1, 40)
      FMA4(c3, cb[11], p1, 44)
      const float h0 = fmaxf((a0 + a1) + (a2 + a3), 0.f);
      const float h1 = fmaxf((c0 + c1) + (c2 + c3), 0.f);

#pragma unroll
      for (int o4 = 0; o4 < 4; ++o4) {
        float4 wv = (o4 == 0) ? u0 : (o4 == 1) ? u1 : (o4 == 2) ? u2 : u3;
        diff0[o4 * 4 + 0] = fmaf(wv.x, h0, diff0[o4 * 4 + 0]);
        diff0[o4 * 4 + 1] = fmaf(wv.y, h0, diff0[o4 * 4 + 1]);
        diff0[o4 * 4 + 2] = fmaf(wv.z, h0, diff0[o4 * 4 + 2]);
        diff0[o4 * 4 + 3] = fmaf(wv.w, h0, diff0[o4 * 4 + 3]);
        diff1[o4 * 4 + 0] = fmaf(wv.x, h1, diff1[o4 * 4 + 0]);
        diff1[o4 * 4 + 1] = fmaf(wv.y, h1, diff1[o4 * 4 + 1]);
        diff1[o4 * 4 + 2] = fmaf(wv.z, h1, diff1[o4 * 4 + 2]);
        diff1[o4 * 4 + 3] = fmaf(wv.w, h1, diff1[o4 * 4 + 3]);
      }
    }
  }

  const float m0 = jax_mask_bit(key0, key1, g0);
  const float m1 = jax_mask_bit(key0, key1, g0 + WW);

  float* nb = nxt + (size_t)b * CC * HWSZ + hw0;
#pragma unroll
  for (int c = 0; c < CC; ++c) {
    nb[c * HWSZ] = fmaf(diff0[c], m0, p0[c]);       // row r
    nb[c * HWSZ + WW] = fmaf(diff1[c], m1, p1[c]);  // row r+1
  }
}

// ---------------------------------------------------------------------------
// Kernel B: 3x3 max-pool on alpha (ch 3), alive gate, write next state
// ---------------------------------------------------------------------------
__global__ __launch_bounds__(256) void ca_step_alive(
    const float* __restrict__ nw, float* __restrict__ out) {
  const int g = blockIdx.x * 256 + threadIdx.x;
  const int b = g >> 14;
  const int hw = g & (HWSZ - 1);
  const int h = hw >> 7;
  const int w = hw & (WW - 1);
  const bool hu = h > 0, hd = h < HH_ - 1, wl = w > 0, wr = w < WW - 1;

  const float* ab = nw + ((size_t)b * CC + 3) * HWSZ + hw;
  float pooled = ab[0];
  if (hu) {
    pooled = fmaxf(pooled, ab[-WW]);
    if (wl) pooled = fmaxf(pooled, ab[-WW - 1]);
    if (wr) pooled = fmaxf(pooled, ab[-WW + 1]);
  }
  if (hd) {
    pooled = fmaxf(pooled, ab[WW]);
    if (wl) pooled = fmaxf(pooled, ab[WW - 1]);
    if (wr) pooled = fmaxf(pooled, ab[WW + 1]);
  }
  if (wl) pooled = fmaxf(pooled, ab[-1]);
  if (wr) pooled = fmaxf(pooled, ab[1]);

  const float alive = (pooled > 0.1f) ? 1.0f : 0.0f;

  const float* nb = nw + (size_t)b * CC * HWSZ + hw;
  float* ob = out + (size_t)b * CC * HWSZ + hw;
#pragma unroll
  for (int c = 0; c < CC; ++c) ob[c * HWSZ] = nb[c * HWSZ] * alive;
}

// ---------------------------------------------------------------------------
extern "C" void kernel_launch(void* const* d_in, const int* in_sizes, int n_in,
                              void* d_out, int out_size, void* d_ws,
                              size_t ws_size, hipStream_t stream) {
  const float* x = (const float*)d_in[0];
  const float* w1 = (const float*)d_in[1];
  const float* b1 = (const float*)d_in[2];
  const float* w2 = (const float*)d_in[3];
  const float* b2 = (const float*)d_in[4];
  // d_in[5] = n_steps (16) — fixed at compile time

  float* out = (float*)d_out;
  float* nbuf = (float*)d_ws;  // NPIX*CC*4 = 8 MB scratch

  // step keys from split(key(42), 16), partitionable threefry
  uint32_t k0s[NSTEPS], k1s[NSTEPS];
  for (int s = 0; s < NSTEPS; ++s)
    threefry2x32(0u, 42u, 0u, (uint32_t)s, &k0s[s], &k1s[s]);

  dim3 gridA(NPIX / 512), blockA(256);  // 256 blocks -> 1 per CU
  dim3 gridB(NPIX / 256), blockB(256);
  for (int s = 0; s < NSTEPS; ++s) {
    const float* src = (s == 0) ? x : out;
    ca_step_mlp<<<gridA, blockA, 0, stream>>>(src, w1, b1, w2, b2, nbuf,
                                              k0s[s], k1s[s]);
    ca_step_alive<<<gridB, blockB, 0, stream>>>(nbuf, out);
  }
}